// Round 8
// baseline (17625.845 us; speedup 1.0000x reference)
//
#include <hip/hip_runtime.h>
#include <cmath>

#define REGP 0.1f
#define NIT 200
#define K2 14.4269504089f        // log2(e)/reg
#define CREF 28.5f               // centering constant for f
#define CLO  23.5f               // u8 quantization lower bound
#define QSV  (17.0f/255.0f)      // quant step
#define QIV  15.0f               // 1/QSV
#define S2V  (QSV*K2)

#define NBLK 256                 // k_sink grid (1 block/CU)
#define NTHR 1024                // 16 waves/block, 4 waves/SIMD
#define NGRP 8
#define GSZ  (NBLK/NGRP)         // 32 arrivals per group counter

typedef float  vf4  __attribute__((ext_vector_type(4)));
typedef short  vbf8 __attribute__((ext_vector_type(8)));
typedef unsigned short vu8 __attribute__((ext_vector_type(8)));

#if defined(__has_builtin) && __has_builtin(__builtin_amdgcn_exp2f)
#define EXP2F(x) __builtin_amdgcn_exp2f(x)
#else
#define EXP2F(x) exp2f(x)
#endif

static __device__ __forceinline__ unsigned short f2bf(float x) {
    unsigned int u = __float_as_uint(x);
    return (unsigned short)((u + 0x7FFFu + ((u >> 16) & 1u)) >> 16);
}

static __device__ __forceinline__ float wave_red_sum(float v) {
    #pragma unroll
    for (int o = 32; o > 0; o >>= 1) v += __shfl_xor(v, o, 64);
    return v;
}

// 16 u8 cost values vs 16 vk values; 4 independent accumulators
static __device__ __forceinline__ void acc16(uint4 c, const vf4* gv, vf4& sacc) {
    #pragma unroll
    for (int d = 0; d < 4; ++d) {
        unsigned x = d == 0 ? c.x : d == 1 ? c.y : d == 2 ? c.z : c.w;
        vf4 g = gv[d];
        sacc[0] += EXP2F(fmaf((float)(x & 0xffu),         -S2V, g[0]));
        sacc[1] += EXP2F(fmaf((float)((x >> 8) & 0xffu),  -S2V, g[1]));
        sacc[2] += EXP2F(fmaf((float)((x >> 16) & 0xffu), -S2V, g[2]));
        sacc[3] += EXP2F(fmaf((float)(x >> 24),           -S2V, g[3]));
    }
}

// ---------------- hierarchical reset-free grid barrier (R7-validated) ----------------
// bar[0]=root; bar[32*(1+g)]=cnt[g]; bar[32*(9+g)]=gen[g]. Monotonic, all
// RELAXED agent atomics (no fences -> no L2 sweeps). __syncthreads() drains
// vmcnt before arrival, completing sc write-through stores at the coherent point.

static __device__ __forceinline__ void gbar(unsigned* bar, unsigned bi, int blk) {
    __syncthreads();
    if (threadIdx.x == 0) {
        int g = blk & (NGRP - 1);
        unsigned* cnt = bar + 32 * (1 + g);
        unsigned* gen = bar + 32 * (9 + g);
        unsigned old = __hip_atomic_fetch_add(cnt, 1u, __ATOMIC_RELAXED, __HIP_MEMORY_SCOPE_AGENT);
        if (old == bi * GSZ - 1u) {                 // last of my group
            unsigned r = __hip_atomic_fetch_add(bar, 1u, __ATOMIC_RELAXED, __HIP_MEMORY_SCOPE_AGENT);
            if (r == bi * NGRP - 1u) {              // last group globally: release all
                #pragma unroll
                for (int k = 0; k < NGRP; ++k)
                    __hip_atomic_store(bar + 32 * (9 + k), bi, __ATOMIC_RELAXED, __HIP_MEMORY_SCOPE_AGENT);
            } else {
                while (__hip_atomic_load(gen, __ATOMIC_RELAXED, __HIP_MEMORY_SCOPE_AGENT) < bi)
                    __builtin_amdgcn_s_sleep(4);
            }
        } else {
            while (__hip_atomic_load(gen, __ATOMIC_RELAXED, __HIP_MEMORY_SCOPE_AGENT) < bi)
                __builtin_amdgcn_s_sleep(4);
        }
    }
    __syncthreads();
}

// ---------------- coherent-bypass stage of vk into LDS, XOR-swizzled ----------------
// logical 16B-granule G stored at physical G ^ ((t>>3)&7).

template<int NG>   // granules (16B) per thread
static __device__ __forceinline__ void stage_vk(const float* src, float* lds) {
    int t = threadIdx.x;
    int xr = (t >> 3) & 7;
    const unsigned long long* p = (const unsigned long long*)src;
    #pragma unroll
    for (int i = 0; i < NG; ++i) {
        int gr = i * NTHR + t;
        unsigned long long lo = __hip_atomic_load((unsigned long long*)&p[gr * 2],
                                                  __ATOMIC_RELAXED, __HIP_MEMORY_SCOPE_AGENT);
        unsigned long long hi = __hip_atomic_load((unsigned long long*)&p[gr * 2 + 1],
                                                  __ATOMIC_RELAXED, __HIP_MEMORY_SCOPE_AGENT);
        int pg = gr ^ xr;
        *(unsigned long long*)(lds + pg * 4)     = lo;
        *(unsigned long long*)(lds + pg * 4 + 2) = hi;
    }
}

// ---------------- prep kernels ----------------

__global__ void k_init(float* gk, float* scalars, unsigned* bar, int M) {
    int i = blockIdx.x * blockDim.x + threadIdx.x;
    if (i < M) gk[i] = 5.0f * K2;        // g=0: gk=(0-0+5)*K2
    if (i < 8) scalars[i] = 0.f;
    if (i < 1024) bar[i] = 0u;
}

__global__ void k_convnorm(const float* __restrict__ X, unsigned short* __restrict__ Xb,
                           float* __restrict__ xx, int D) {
    int row = blockIdx.x, lane = threadIdx.x;
    const float* p = X + (size_t)row * D;
    unsigned short* q = Xb + (size_t)row * D;
    float sq = 0.f;
    for (int base = lane * 8; base < D; base += 512) {
        vf4 a = *(const vf4*)(p + base);
        vf4 b = *(const vf4*)(p + base + 4);
        vu8 o;
        #pragma unroll
        for (int e = 0; e < 4; ++e) {
            o[e]     = f2bf(a[e]);
            o[4 + e] = f2bf(b[e]);
            sq += a[e] * a[e] + b[e] * b[e];
        }
        *(vu8*)(q + base) = o;
    }
    sq = wave_red_sum(sq);
    if (lane == 0) xx[row] = sq;
}

__global__ void k_sumtgt(const float* __restrict__ t, float* scalars, int M) {
    __shared__ float red[4];
    float s = 0.f;
    for (int i = threadIdx.x; i < M; i += 256) s += t[i];
    s = wave_red_sum(s);
    if ((threadIdx.x & 63) == 0) red[threadIdx.x >> 6] = s;
    __syncthreads();
    if (threadIdx.x == 0) scalars[3] = logf(red[0] + red[1] + red[2] + red[3]);
}

__global__ void k_rlb(const float* __restrict__ tgt, const float* __restrict__ scalars,
                      float* __restrict__ rlb, int M) {
    int j = blockIdx.x * 256 + threadIdx.x;
    if (j < M) rlb[j] = REGP * (logf(tgt[j]) - scalars[3]);
}

// ---------------- cost matrix: OUT[i][j] = quant_u8(sqrt(an[i]+bn[j]-2 A_i.B_j)) ----------------

__global__ __launch_bounds__(256, 2)
void k_gemm(const unsigned short* __restrict__ A, const unsigned short* __restrict__ B,
            const float* __restrict__ an, const float* __restrict__ bn,
            unsigned char* __restrict__ OUT, int ldo, int D) {
    int m0 = blockIdx.y * 128, n0 = blockIdx.x * 128;
    int wave = threadIdx.x >> 6, lane = threadIdx.x & 63;
    int lr = lane & 15, lk = (lane >> 4) * 8;
    const unsigned short* ax = A + (size_t)(m0 + wave * 32 + lr) * D + lk;
    const unsigned short* bx = B + (size_t)(n0 + lr) * D + lk;
    vf4 acc[2][8];
    #pragma unroll
    for (int r = 0; r < 2; ++r)
        #pragma unroll
        for (int c = 0; c < 8; ++c) acc[r][c] = (vf4){0.f, 0.f, 0.f, 0.f};

    for (int k = 0; k < D; k += 32) {
        vbf8 a0 = *(const vbf8*)(ax + k);
        vbf8 a1 = *(const vbf8*)(ax + 16 * D + k);
        #pragma unroll
        for (int c = 0; c < 8; ++c) {
            vbf8 b = *(const vbf8*)(bx + (size_t)c * 16 * D + k);
            acc[0][c] = __builtin_amdgcn_mfma_f32_16x16x32_bf16(a0, b, acc[0][c], 0, 0, 0);
            acc[1][c] = __builtin_amdgcn_mfma_f32_16x16x32_bf16(a1, b, acc[1][c], 0, 0, 0);
        }
    }
    int rbase = m0 + wave * 32 + (lane >> 4) * 4;
    #pragma unroll
    for (int r = 0; r < 2; ++r) {
        #pragma unroll
        for (int q = 0; q < 4; ++q) {
            int i = rbase + r * 16 + q;
            float xi = an[i];
            #pragma unroll
            for (int c = 0; c < 8; ++c) {
                int j = n0 + c * 16 + lr;
                float sq = xi + bn[j] - 2.f * acc[r][c][q];
                float cv = sqrtf(fmaxf(sq, 1e-12f));
                float qv = fminf(fmaxf((cv - CLO) * QIV, 0.f), 255.f);
                OUT[(size_t)i * ldo + j] = (unsigned char)(qv + 0.5f);
            }
        }
    }
}

// ---------------- persistent sinkhorn: 200 iterations ----------------
// 256 blocks x 1024 threads (16 waves: 4/SIMD). Each wave: 2 rows x half width,
// all C-tile loads prefetched up front. Cross-half combine via sred[32][2].

__global__ __launch_bounds__(1024, 4)
void k_sink(const unsigned char* __restrict__ C, const unsigned char* __restrict__ CT,
            float* __restrict__ f, float* __restrict__ g,
            float* fk, float* gk,
            const float* __restrict__ rlb, float rla,
            unsigned* bar, int N, int M) {
    __shared__ float vlds[8192];
    __shared__ float sred[32][2];
    int blk = blockIdx.x;
    int tid = threadIdx.x;
    int w = tid >> 6, l = tid & 63;
    int rp = w & 7, h = w >> 3;          // rowpair 0..7, half 0..1
    int xr = (l >> 1) & 7;
    unsigned bi = 0;
    for (int it = 0; it < NIT; ++it) {
        // ---- f-update: 16 rows of C (width M=8192); wave covers cols [h*4096, +4096) ----
        stage_vk<2>(gk, vlds);           // 8192 floats
        __syncthreads();
        {
            int rA = blk * 16 + rp * 2;
            const unsigned char* cpA = C + (size_t)rA * M + h * 4096 + l * 16;
            const unsigned char* cpB = cpA + M;
            uint4 ca[4], cb[4];
            #pragma unroll
            for (int ch = 0; ch < 4; ++ch) {
                ca[ch] = *(const uint4*)(cpA + ch * 1024);
                cb[ch] = *(const uint4*)(cpB + ch * 1024);
            }
            vf4 sA = (vf4){0.f,0.f,0.f,0.f}, sB = (vf4){0.f,0.f,0.f,0.f};
            #pragma unroll
            for (int ch = 0; ch < 4; ++ch) {
                int G0 = h * 1024 + ch * 256 + l * 4;
                vf4 gv[4];
                #pragma unroll
                for (int q = 0; q < 4; ++q)
                    gv[q] = *(const vf4*)(vlds + (size_t)((G0 + q) ^ xr) * 4);
                acc16(ca[ch], gv, sA);
                acc16(cb[ch], gv, sB);
            }
            float s0 = wave_red_sum(sA[0] + sA[1] + sA[2] + sA[3]);
            float s1 = wave_red_sum(sB[0] + sB[1] + sB[2] + sB[3]);
            if (l == 0) { sred[rp * 2][h] = s0; sred[rp * 2 + 1][h] = s1; }
            __syncthreads();
            if (tid < 16) {
                float s = sred[tid][0] + sred[tid][1];
                int row = blk * 16 + tid;
                float val = rla + CREF - log2f(s) * (1.0f / K2);
                f[row] = val;
                __hip_atomic_store(&fk[row], (val - CLO) * K2,
                                   __ATOMIC_RELAXED, __HIP_MEMORY_SCOPE_AGENT);
            }
        }
        gbar(bar, ++bi, blk);
        // ---- g-update: 32 rows of CT (width N=4096); wave covers cols [h*2048, +2048) ----
        stage_vk<1>(fk, vlds);           // 4096 floats
        __syncthreads();
        {
            int r0 = blk * 32 + rp * 2;
            const unsigned char* cpA0 = CT + (size_t)r0 * N + h * 2048 + l * 16;
            const unsigned char* cpB0 = cpA0 + N;
            const unsigned char* cpA1 = cpA0 + (size_t)16 * N;
            const unsigned char* cpB1 = cpB0 + (size_t)16 * N;
            uint4 ca0[2], cb0[2], ca1[2], cb1[2];
            #pragma unroll
            for (int ch = 0; ch < 2; ++ch) {
                ca0[ch] = *(const uint4*)(cpA0 + ch * 1024);
                cb0[ch] = *(const uint4*)(cpB0 + ch * 1024);
                ca1[ch] = *(const uint4*)(cpA1 + ch * 1024);
                cb1[ch] = *(const uint4*)(cpB1 + ch * 1024);
            }
            vf4 sA0 = (vf4){0.f,0.f,0.f,0.f}, sB0 = (vf4){0.f,0.f,0.f,0.f};
            vf4 sA1 = (vf4){0.f,0.f,0.f,0.f}, sB1 = (vf4){0.f,0.f,0.f,0.f};
            #pragma unroll
            for (int ch = 0; ch < 2; ++ch) {
                int G0 = h * 512 + ch * 256 + l * 4;
                vf4 gv[4];
                #pragma unroll
                for (int q = 0; q < 4; ++q)
                    gv[q] = *(const vf4*)(vlds + (size_t)((G0 + q) ^ xr) * 4);
                acc16(ca0[ch], gv, sA0);
                acc16(cb0[ch], gv, sB0);
                acc16(ca1[ch], gv, sA1);
                acc16(cb1[ch], gv, sB1);
            }
            float t0 = wave_red_sum(sA0[0] + sA0[1] + sA0[2] + sA0[3]);
            float t1 = wave_red_sum(sB0[0] + sB0[1] + sB0[2] + sB0[3]);
            float t2 = wave_red_sum(sA1[0] + sA1[1] + sA1[2] + sA1[3]);
            float t3 = wave_red_sum(sB1[0] + sB1[1] + sB1[2] + sB1[3]);
            if (l == 0) {
                sred[rp * 2][h]          = t0;
                sred[rp * 2 + 1][h]      = t1;
                sred[16 + rp * 2][h]     = t2;
                sred[16 + rp * 2 + 1][h] = t3;
            }
            __syncthreads();
            if (tid < 32) {
                float s = sred[tid][0] + sred[tid][1];
                int row = blk * 32 + tid;
                float val = rlb[row] - log2f(s) * (1.0f / K2);
                g[row] = val;
                __hip_atomic_store(&gk[row], (val + (CREF - CLO)) * K2,
                                   __ATOMIC_RELAXED, __HIP_MEMORY_SCOPE_AGENT);
            }
        }
        gbar(bar, ++bi, blk);
    }
}

// ---------------- epilogue: sum P*C' ----------------

__global__ __launch_bounds__(256)
void k_ot(const unsigned char* __restrict__ C, const float* __restrict__ f,
          const float* __restrict__ gk, float* __restrict__ scalars, int M) {
    int row = blockIdx.x * 4 + (threadIdx.x >> 6);
    int lane = threadIdx.x & 63;
    const unsigned char* cp = C + (size_t)row * M;
    float fk2 = (f[row] - CREF) * K2;
    float acc = 0.f;
    for (int base = lane * 16; base < M; base += 1024) {
        uint4 cw = *(const uint4*)(cp + base);
        #pragma unroll
        for (int d = 0; d < 4; ++d) {
            unsigned x = d == 0 ? cw.x : d == 1 ? cw.y : d == 2 ? cw.z : cw.w;
            vf4 g = *(const vf4*)(gk + base + d * 4);
            #pragma unroll
            for (int e = 0; e < 4; ++e) {
                float uf = (float)((x >> (8 * e)) & 0xffu);
                float t = fmaf(uf, -S2V, fk2 + g[e]);
                float cval = fmaf(uf, QSV, CLO);
                acc = fmaf(EXP2F(t), cval, acc);
            }
        }
    }
    acc = wave_red_sum(acc);
    if (lane == 0) atomicAdd(&scalars[0], acc);
}

__global__ void k_dist(const float* __restrict__ X, const float* __restrict__ Y,
                       const int* __restrict__ aligned, float* __restrict__ scalars, int D) {
    int i = blockIdx.x, lane = threadIdx.x;
    int a = aligned[i];
    if (a == -1) return;
    const float* xp = X + (size_t)i * D;
    const float* yp = Y + (size_t)a * D;
    float sq = 0.f;
    for (int base = lane * 8; base < D; base += 512) {
        vf4 x0 = *(const vf4*)(xp + base), x1 = *(const vf4*)(xp + base + 4);
        vf4 y0 = *(const vf4*)(yp + base), y1 = *(const vf4*)(yp + base + 4);
        #pragma unroll
        for (int e = 0; e < 4; ++e) {
            float d0 = x0[e] - y0[e], d1 = x1[e] - y1[e];
            sq += d0 * d0 + d1 * d1;
        }
    }
    sq = wave_red_sum(sq);
    if (lane == 0) { atomicAdd(&scalars[1], sq); atomicAdd(&scalars[2], 1.0f); }
}

__global__ void k_final(float* out, const float* __restrict__ scalars, int D) {
    float cnt = scalars[2];
    float dist = cnt > 0.f ? scalars[1] / (cnt * (float)D) : 0.f;
    out[0] = scalars[0] + dist;
}

// ---------------- host ----------------

extern "C" void kernel_launch(void* const* d_in, const int* in_sizes, int n_in,
                              void* d_out, int out_size, void* d_ws, size_t ws_size,
                              hipStream_t stream) {
    const float* X = (const float*)d_in[0];
    const float* Y = (const float*)d_in[1];
    const int* aligned = (const int*)d_in[2];
    const float* tgt = (const float*)d_in[3];
    int N = in_sizes[2];              // 4096
    int M = in_sizes[3];              // 8192
    int D = in_sizes[0] / N;          // 512
    float* out = (float*)d_out;

    char* w = (char*)d_ws;
    size_t off = 0;
    auto alloc = [&](size_t bytes) -> void* {
        void* p = w + off;
        off += (bytes + 255) & ~(size_t)255;
        return p;
    };
    unsigned short* Xb = (unsigned short*)alloc((size_t)N * D * 2);
    unsigned short* Yb = (unsigned short*)alloc((size_t)M * D * 2);
    unsigned char* C  = (unsigned char*)alloc((size_t)N * M);
    unsigned char* CT = (unsigned char*)alloc((size_t)N * M);
    float* xx  = (float*)alloc((size_t)N * 4);
    float* yy  = (float*)alloc((size_t)M * 4);
    float* f   = (float*)alloc((size_t)N * 4);
    float* g   = (float*)alloc((size_t)M * 4);
    float* fk  = (float*)alloc((size_t)N * 4);
    float* gk  = (float*)alloc((size_t)M * 4);
    float* rlb = (float*)alloc((size_t)M * 4);
    float* scalars = (float*)alloc(64);
    unsigned* bar = (unsigned*)alloc(4096);
    if (off > ws_size) return;

    float rla = -REGP * logf((float)N);

    k_init<<<dim3((M + 255) / 256), 256, 0, stream>>>(gk, scalars, bar, M);
    k_convnorm<<<dim3(N), 64, 0, stream>>>(X, Xb, xx, D);
    k_convnorm<<<dim3(M), 64, 0, stream>>>(Y, Yb, yy, D);
    k_sumtgt<<<1, 256, 0, stream>>>(tgt, scalars, M);
    k_rlb<<<dim3((M + 255) / 256), 256, 0, stream>>>(tgt, scalars, rlb, M);
    k_gemm<<<dim3(M / 128, N / 128), 256, 0, stream>>>(Xb, Yb, xx, yy, C,  M, D);
    k_gemm<<<dim3(N / 128, M / 128), 256, 0, stream>>>(Yb, Xb, yy, xx, CT, N, D);

    // persistent sinkhorn: one launch, hierarchical software barrier, 200 iterations
    k_sink<<<dim3(NBLK), NTHR, 0, stream>>>(C, CT, f, g, fk, gk, rlb, rla, bar, N, M);

    k_ot<<<dim3(N / 4), 256, 0, stream>>>(C, f, gk, scalars, M);
    k_dist<<<dim3(N), 64, 0, stream>>>(X, Y, aligned, scalars, D);
    k_final<<<1, 1, 0, stream>>>(out, scalars, D);
}

// Round 9
// 5444.014 us; speedup vs baseline: 3.2377x; 3.2377x over previous
//
#include <hip/hip_runtime.h>
#include <cmath>

#define REGP 0.1f
#define NIT 200
#define K2 14.4269504089f        // log2(e)/reg
#define CREF 28.5f               // centering constant for f
#define CLO  23.5f               // u8 quantization lower bound
#define QSV  (17.0f/255.0f)      // quant step
#define QIV  15.0f               // 1/QSV
#define S2V  (QSV*K2)

#define NBLK 256                 // k_sink grid (1 block/CU, LDS-bound)
#define NTHR 512                 // 8 waves/block
#define NGRP 8
#define GSZ  (NBLK/NGRP)         // 32 arrivals per group counter

// k_sink dynamic LDS layout (bytes)
#define SM_C    0                // u8 C rows: 16 x 8192 = 131072
#define SM_GKH  131072           // staged gk half: 4096 f32 = 16384
#define SM_FKL  147456           // fk local: 16 f32
#define SM_SRED 147520           // row-lse partials: 16 f32
#define SM_RED2 147584           // phase-B reduce: 16x32 f32 = 2048
#define SM_SIZE 149632

typedef float  vf4  __attribute__((ext_vector_type(4)));
typedef short  vbf8 __attribute__((ext_vector_type(8)));
typedef unsigned short vu8 __attribute__((ext_vector_type(8)));

#if defined(__has_builtin) && __has_builtin(__builtin_amdgcn_exp2f)
#define EXP2F(x) __builtin_amdgcn_exp2f(x)
#else
#define EXP2F(x) exp2f(x)
#endif

static __device__ __forceinline__ unsigned short f2bf(float x) {
    unsigned int u = __float_as_uint(x);
    return (unsigned short)((u + 0x7FFFu + ((u >> 16) & 1u)) >> 16);
}

static __device__ __forceinline__ float wave_red_sum(float v) {
    #pragma unroll
    for (int o = 32; o > 0; o >>= 1) v += __shfl_xor(v, o, 64);
    return v;
}

// 16 u8 cost values vs 16 vk values; 4 independent accumulators
static __device__ __forceinline__ void acc16(uint4 c, const vf4* gv, vf4& sacc) {
    #pragma unroll
    for (int d = 0; d < 4; ++d) {
        unsigned x = d == 0 ? c.x : d == 1 ? c.y : d == 2 ? c.z : c.w;
        vf4 g = gv[d];
        sacc[0] += EXP2F(fmaf((float)(x & 0xffu),         -S2V, g[0]));
        sacc[1] += EXP2F(fmaf((float)((x >> 8) & 0xffu),  -S2V, g[1]));
        sacc[2] += EXP2F(fmaf((float)((x >> 16) & 0xffu), -S2V, g[2]));
        sacc[3] += EXP2F(fmaf((float)(x >> 24),           -S2V, g[3]));
    }
}

// ---------------- hierarchical reset-free grid barrier (R7-validated) ----------------

static __device__ __forceinline__ void gbar(unsigned* bar, unsigned bi, int blk) {
    __syncthreads();
    if (threadIdx.x == 0) {
        int g = blk & (NGRP - 1);
        unsigned* cnt = bar + 32 * (1 + g);
        unsigned* gen = bar + 32 * (9 + g);
        unsigned old = __hip_atomic_fetch_add(cnt, 1u, __ATOMIC_RELAXED, __HIP_MEMORY_SCOPE_AGENT);
        if (old == bi * GSZ - 1u) {                 // last of my group
            unsigned r = __hip_atomic_fetch_add(bar, 1u, __ATOMIC_RELAXED, __HIP_MEMORY_SCOPE_AGENT);
            if (r == bi * NGRP - 1u) {              // last group globally: release all
                #pragma unroll
                for (int k = 0; k < NGRP; ++k)
                    __hip_atomic_store(bar + 32 * (9 + k), bi, __ATOMIC_RELAXED, __HIP_MEMORY_SCOPE_AGENT);
            } else {
                while (__hip_atomic_load(gen, __ATOMIC_RELAXED, __HIP_MEMORY_SCOPE_AGENT) < bi)
                    __builtin_amdgcn_s_sleep(4);
            }
        } else {
            while (__hip_atomic_load(gen, __ATOMIC_RELAXED, __HIP_MEMORY_SCOPE_AGENT) < bi)
                __builtin_amdgcn_s_sleep(4);
        }
    }
    __syncthreads();
}

// ---------------- prep kernels ----------------

__global__ void k_init(float* gk, float* scalars, unsigned* bar, int M) {
    int i = blockIdx.x * blockDim.x + threadIdx.x;
    if (i < M) gk[i] = 5.0f * K2;        // g=0: gk=(0+CREF-CLO)*K2
    if (i < 8) scalars[i] = 0.f;
    if (i < 1024) bar[i] = 0u;
}

__global__ void k_convnorm(const float* __restrict__ X, unsigned short* __restrict__ Xb,
                           float* __restrict__ xx, int D) {
    int row = blockIdx.x, lane = threadIdx.x;
    const float* p = X + (size_t)row * D;
    unsigned short* q = Xb + (size_t)row * D;
    float sq = 0.f;
    for (int base = lane * 8; base < D; base += 512) {
        vf4 a = *(const vf4*)(p + base);
        vf4 b = *(const vf4*)(p + base + 4);
        vu8 o;
        #pragma unroll
        for (int e = 0; e < 4; ++e) {
            o[e]     = f2bf(a[e]);
            o[4 + e] = f2bf(b[e]);
            sq += a[e] * a[e] + b[e] * b[e];
        }
        *(vu8*)(q + base) = o;
    }
    sq = wave_red_sum(sq);
    if (lane == 0) xx[row] = sq;
}

__global__ void k_sumtgt(const float* __restrict__ t, float* scalars, int M) {
    __shared__ float red[4];
    float s = 0.f;
    for (int i = threadIdx.x; i < M; i += 256) s += t[i];
    s = wave_red_sum(s);
    if ((threadIdx.x & 63) == 0) red[threadIdx.x >> 6] = s;
    __syncthreads();
    if (threadIdx.x == 0) scalars[3] = logf(red[0] + red[1] + red[2] + red[3]);
}

__global__ void k_rlb(const float* __restrict__ tgt, const float* __restrict__ scalars,
                      float* __restrict__ rlb, int M) {
    int j = blockIdx.x * 256 + threadIdx.x;
    if (j < M) rlb[j] = REGP * (logf(tgt[j]) - scalars[3]);
}

// ---------------- cost matrix: OUT[i][j] = quant_u8(sqrt(an[i]+bn[j]-2 A_i.B_j)) ----------------

__global__ __launch_bounds__(256, 2)
void k_gemm(const unsigned short* __restrict__ A, const unsigned short* __restrict__ B,
            const float* __restrict__ an, const float* __restrict__ bn,
            unsigned char* __restrict__ OUT, int ldo, int D) {
    int m0 = blockIdx.y * 128, n0 = blockIdx.x * 128;
    int wave = threadIdx.x >> 6, lane = threadIdx.x & 63;
    int lr = lane & 15, lk = (lane >> 4) * 8;
    const unsigned short* ax = A + (size_t)(m0 + wave * 32 + lr) * D + lk;
    const unsigned short* bx = B + (size_t)(n0 + lr) * D + lk;
    vf4 acc[2][8];
    #pragma unroll
    for (int r = 0; r < 2; ++r)
        #pragma unroll
        for (int c = 0; c < 8; ++c) acc[r][c] = (vf4){0.f, 0.f, 0.f, 0.f};

    for (int k = 0; k < D; k += 32) {
        vbf8 a0 = *(const vbf8*)(ax + k);
        vbf8 a1 = *(const vbf8*)(ax + 16 * D + k);
        #pragma unroll
        for (int c = 0; c < 8; ++c) {
            vbf8 b = *(const vbf8*)(bx + (size_t)c * 16 * D + k);
            acc[0][c] = __builtin_amdgcn_mfma_f32_16x16x32_bf16(a0, b, acc[0][c], 0, 0, 0);
            acc[1][c] = __builtin_amdgcn_mfma_f32_16x16x32_bf16(a1, b, acc[1][c], 0, 0, 0);
        }
    }
    int rbase = m0 + wave * 32 + (lane >> 4) * 4;
    #pragma unroll
    for (int r = 0; r < 2; ++r) {
        #pragma unroll
        for (int q = 0; q < 4; ++q) {
            int i = rbase + r * 16 + q;
            float xi = an[i];
            #pragma unroll
            for (int c = 0; c < 8; ++c) {
                int j = n0 + c * 16 + lr;
                float sq = xi + bn[j] - 2.f * acc[r][c][q];
                float cv = sqrtf(fmaxf(sq, 1e-12f));
                float qv = fminf(fmaxf((cv - CLO) * QIV, 0.f), 255.f);
                OUT[(size_t)i * ldo + j] = (unsigned char)(qv + 0.5f);
            }
        }
    }
}

// ---------------- persistent sinkhorn: C lives in LDS; no CT ----------------
// 256 blocks x 512 thr, 1 block/CU (149.6 KB LDS). Block owns 16 rows of C.
// Per iter: phase A: sweep1 row-lse (gk staged per half) -> f local;
//                    sweep2 col-contrib with fresh f -> colpart[blk][:] (sc)
//           gbar;  phase B: reduce colpart over 256 blocks for 32 cols -> gk (sc)
//           gbar.

__global__ __launch_bounds__(NTHR, 1)
void k_sink(const unsigned char* __restrict__ C, float* __restrict__ f,
            float* gk, float* colpart, const float* __restrict__ rlb,
            float rla, unsigned* bar, int N, int M) {
    extern __shared__ char smem[];
    unsigned char* cl = (unsigned char*)(smem + SM_C);
    float* gkh  = (float*)(smem + SM_GKH);
    float* fkl  = (float*)(smem + SM_FKL);
    float* sred = (float*)(smem + SM_SRED);
    float* red2 = (float*)(smem + SM_RED2);
    int blk = blockIdx.x, tid = threadIdx.x;
    int w = tid >> 6, l = tid & 63;
    int xr = (l >> 1) & 7;

    // one-time: load my 16 rows of C into LDS (128 KB)
    {
        const unsigned char* src = C + (size_t)blk * 16 * M;
        #pragma unroll
        for (int r = 0; r < 16; ++r)
            *(uint4*)(cl + r * 8192 + tid * 16) =
                *(const uint4*)(src + (size_t)r * M + tid * 16);
    }

    unsigned bi = 0;
    for (int it = 0; it < NIT; ++it) {
        // ---------- phase A: sweep1 (row-lse), 2 rows/wave, 2 column-halves ----------
        vf4 sA = (vf4){0.f,0.f,0.f,0.f}, sB = (vf4){0.f,0.f,0.f,0.f};
        const unsigned char* r0p = cl + (w * 2) * 8192;
        const unsigned char* r1p = r0p + 8192;
        #pragma unroll
        for (int H = 0; H < 2; ++H) {
            __syncthreads();                  // gkh safe to overwrite
            {   // stage gk[H*4096 ..) into gkh, granule-swizzled (sc-bypass loads)
                const unsigned long long* p = (const unsigned long long*)(gk + H * 4096);
                #pragma unroll
                for (int i = 0; i < 2; ++i) {
                    int gr = i * NTHR + tid;
                    unsigned long long lo = __hip_atomic_load(&p[(size_t)gr * 2],
                                                __ATOMIC_RELAXED, __HIP_MEMORY_SCOPE_AGENT);
                    unsigned long long hi = __hip_atomic_load(&p[(size_t)gr * 2 + 1],
                                                __ATOMIC_RELAXED, __HIP_MEMORY_SCOPE_AGENT);
                    int pg = gr ^ ((gr >> 3) & 7);
                    *(unsigned long long*)(gkh + pg * 4)     = lo;
                    *(unsigned long long*)(gkh + pg * 4 + 2) = hi;
                }
            }
            __syncthreads();
            #pragma unroll
            for (int ch = 0; ch < 4; ++ch) {
                uint4 a = *(const uint4*)(r0p + H * 4096 + ch * 1024 + l * 16);
                uint4 b = *(const uint4*)(r1p + H * 4096 + ch * 1024 + l * 16);
                int G0 = ch * 256 + l * 4;
                vf4 gv[4];
                #pragma unroll
                for (int q = 0; q < 4; ++q)
                    gv[q] = *(const vf4*)(gkh + (size_t)((G0 + q) ^ xr) * 4);
                acc16(a, gv, sA);
                acc16(b, gv, sB);
            }
        }
        float s0 = wave_red_sum(sA[0] + sA[1] + sA[2] + sA[3]);
        float s1 = wave_red_sum(sB[0] + sB[1] + sB[2] + sB[3]);
        if (l == 0) { sred[w * 2] = s0; sred[w * 2 + 1] = s1; }
        __syncthreads();
        if (tid < 16) {
            float val = rla + CREF - log2f(sred[tid]) * (1.0f / K2);
            f[blk * 16 + tid] = val;          // plain; flushed at kernel end for k_ot
            fkl[tid] = (val - CLO) * K2;
        }
        __syncthreads();
        // ---------- phase A: sweep2 (column contributions), lane owns 16 cols ----------
        {
            float acc[16];
            #pragma unroll
            for (int k = 0; k < 16; ++k) acc[k] = 0.f;
            const unsigned char* cp = cl + w * 1024 + l * 16;
            #pragma unroll
            for (int r = 0; r < 16; ++r) {
                uint4 cw = *(const uint4*)(cp + r * 8192);
                float fr = fkl[r];
                #pragma unroll
                for (int d = 0; d < 4; ++d) {
                    unsigned x = d == 0 ? cw.x : d == 1 ? cw.y : d == 2 ? cw.z : cw.w;
                    #pragma unroll
                    for (int e = 0; e < 4; ++e)
                        acc[d * 4 + e] += EXP2F(fmaf((float)((x >> (8 * e)) & 0xffu), -S2V, fr));
                }
            }
            float* dst = colpart + (size_t)blk * M + w * 1024 + l * 16;
            #pragma unroll
            for (int k = 0; k < 16; k += 2) {
                unsigned long long v = (unsigned long long)__float_as_uint(acc[k])
                                     | ((unsigned long long)__float_as_uint(acc[k + 1]) << 32);
                __hip_atomic_store((unsigned long long*)(dst + k), v,
                                   __ATOMIC_RELAXED, __HIP_MEMORY_SCOPE_AGENT);
            }
        }
        gbar(bar, ++bi, blk);
        // ---------- phase B: reduce 256 partials for cols blk*32 .. +31 ----------
        {
            int c32 = tid & 31, p0 = tid >> 5;
            int col = blk * 32 + c32;
            float s = 0.f;
            #pragma unroll
            for (int k = 0; k < 16; ++k) {
                int p = p0 + k * 16;
                s += __hip_atomic_load(colpart + (size_t)p * M + col,
                                       __ATOMIC_RELAXED, __HIP_MEMORY_SCOPE_AGENT);
            }
            red2[p0 * 32 + c32] = s;
        }
        __syncthreads();
        if (tid < 32) {
            float s = 0.f;
            #pragma unroll
            for (int p = 0; p < 16; ++p) s += red2[p * 32 + tid];
            int col = blk * 32 + tid;
            float kv = (rlb[col] - log2f(s) * (1.0f / K2) + (CREF - CLO)) * K2;
            __hip_atomic_store(gk + col, kv, __ATOMIC_RELAXED, __HIP_MEMORY_SCOPE_AGENT);
        }
        gbar(bar, ++bi, blk);
    }
}

// ---------------- epilogue: sum P*C' ----------------

__global__ __launch_bounds__(256)
void k_ot(const unsigned char* __restrict__ C, const float* __restrict__ f,
          const float* __restrict__ gk, float* __restrict__ scalars, int M) {
    int row = blockIdx.x * 4 + (threadIdx.x >> 6);
    int lane = threadIdx.x & 63;
    const unsigned char* cp = C + (size_t)row * M;
    float fk2 = (f[row] - CREF) * K2;
    float acc = 0.f;
    for (int base = lane * 16; base < M; base += 1024) {
        uint4 cw = *(const uint4*)(cp + base);
        #pragma unroll
        for (int d = 0; d < 4; ++d) {
            unsigned x = d == 0 ? cw.x : d == 1 ? cw.y : d == 2 ? cw.z : cw.w;
            vf4 g = *(const vf4*)(gk + base + d * 4);
            #pragma unroll
            for (int e = 0; e < 4; ++e) {
                float uf = (float)((x >> (8 * e)) & 0xffu);
                float t = fmaf(uf, -S2V, fk2 + g[e]);
                float cval = fmaf(uf, QSV, CLO);
                acc = fmaf(EXP2F(t), cval, acc);
            }
        }
    }
    acc = wave_red_sum(acc);
    if (lane == 0) atomicAdd(&scalars[0], acc);
}

__global__ void k_dist(const float* __restrict__ X, const float* __restrict__ Y,
                       const int* __restrict__ aligned, float* __restrict__ scalars, int D) {
    int i = blockIdx.x, lane = threadIdx.x;
    int a = aligned[i];
    if (a == -1) return;
    const float* xp = X + (size_t)i * D;
    const float* yp = Y + (size_t)a * D;
    float sq = 0.f;
    for (int base = lane * 8; base < D; base += 512) {
        vf4 x0 = *(const vf4*)(xp + base), x1 = *(const vf4*)(xp + base + 4);
        vf4 y0 = *(const vf4*)(yp + base), y1 = *(const vf4*)(yp + base + 4);
        #pragma unroll
        for (int e = 0; e < 4; ++e) {
            float d0 = x0[e] - y0[e], d1 = x1[e] - y1[e];
            sq += d0 * d0 + d1 * d1;
        }
    }
    sq = wave_red_sum(sq);
    if (lane == 0) { atomicAdd(&scalars[1], sq); atomicAdd(&scalars[2], 1.0f); }
}

__global__ void k_final(float* out, const float* __restrict__ scalars, int D) {
    float cnt = scalars[2];
    float dist = cnt > 0.f ? scalars[1] / (cnt * (float)D) : 0.f;
    out[0] = scalars[0] + dist;
}

// ---------------- host ----------------

extern "C" void kernel_launch(void* const* d_in, const int* in_sizes, int n_in,
                              void* d_out, int out_size, void* d_ws, size_t ws_size,
                              hipStream_t stream) {
    const float* X = (const float*)d_in[0];
    const float* Y = (const float*)d_in[1];
    const int* aligned = (const int*)d_in[2];
    const float* tgt = (const float*)d_in[3];
    int N = in_sizes[2];              // 4096
    int M = in_sizes[3];              // 8192
    int D = in_sizes[0] / N;          // 512
    float* out = (float*)d_out;

    char* w = (char*)d_ws;
    size_t off = 0;
    auto alloc = [&](size_t bytes) -> void* {
        void* p = w + off;
        off += (bytes + 255) & ~(size_t)255;
        return p;
    };
    unsigned short* Xb = (unsigned short*)alloc((size_t)N * D * 2);
    unsigned short* Yb = (unsigned short*)alloc((size_t)M * D * 2);
    unsigned char* C  = (unsigned char*)alloc((size_t)N * M);
    float* colpart = (float*)alloc((size_t)NBLK * M * 4);
    float* xx  = (float*)alloc((size_t)N * 4);
    float* yy  = (float*)alloc((size_t)M * 4);
    float* f   = (float*)alloc((size_t)N * 4);
    float* gk  = (float*)alloc((size_t)M * 4);
    float* rlb = (float*)alloc((size_t)M * 4);
    float* scalars = (float*)alloc(64);
    unsigned* bar = (unsigned*)alloc(4096);
    if (off > ws_size) return;

    float rla = -REGP * logf((float)N);

    // opt-in to >64KB dynamic LDS for k_sink (idempotent, non-stream, graph-safe)
    hipFuncSetAttribute((const void*)k_sink,
                        hipFuncAttributeMaxDynamicSharedMemorySize, SM_SIZE);

    k_init<<<dim3((M + 255) / 256), 256, 0, stream>>>(gk, scalars, bar, M);
    k_convnorm<<<dim3(N), 64, 0, stream>>>(X, Xb, xx, D);
    k_convnorm<<<dim3(M), 64, 0, stream>>>(Y, Yb, yy, D);
    k_sumtgt<<<1, 256, 0, stream>>>(tgt, scalars, M);
    k_rlb<<<dim3((M + 255) / 256), 256, 0, stream>>>(tgt, scalars, rlb, M);
    k_gemm<<<dim3(M / 128, N / 128), 256, 0, stream>>>(Xb, Yb, xx, yy, C, M, D);

    // persistent sinkhorn: one launch, LDS-resident C, hierarchical barrier
    k_sink<<<dim3(NBLK), NTHR, SM_SIZE, stream>>>(C, f, gk, colpart, rlb, rla, bar, N, M);

    k_ot<<<dim3(N / 4), 256, 0, stream>>>(C, f, gk, scalars, M);
    k_dist<<<dim3(N), 64, 0, stream>>>(X, Y, aligned, scalars, D);
    k_final<<<1, 1, 0, stream>>>(out, scalars, D);
}